// Round 6
// baseline (2986.122 us; speedup 1.0000x reference)
//
#include <hip/hip_runtime.h>

// DTW accumulated-cost, output = last column. N=65536 rows (input), K=512 cols (kernel).
// Anti-diagonal recurrence with E[j]=min(A_t[j],A_{t-1}[j]):
//   A_{t+1}[j] = min(A_t[j], E_t[j-1]) + (k[j]-x[i])^2 ,  i = t+1-j
// R6: 8 waves (512 thr) x 64-column bands, ONE column per lane => 2 waves/SIMD.
// R2/R3/R5 all plateaued at 76-81 cyc/diag despite 14..20-instr loops =>
// single-wave-per-SIMD issue cadence (~4 cyc/instr) was binding. Two waves/SIMD
// interleave issue; per-wave work halved to ~10 slots/diag => ~40 cyc/diag.
// Boundary pipeline: skewed-chunk barriers, LDS rings (R3-verified DPP patterns).

#define K_LEN 512
#define N_LEN 65536
#define PAD_L 512
#define PAD_R 1024
#define XPAD_TOTAL (PAD_L + N_LEN + PAD_R) // 67072 floats = 268288 B of d_ws
#define BIGX 1e20f
#define NCHUNK 1032                        // 1032*64 = 66048 >= N+K-1 = 66047 diagonals
#define RING 256                           // ring entries per boundary buffer (4 chunks)
#define NWAVE 8                            // 8 bands of 64 columns
#define INIT_RING 7                        // rings 0..6: waves 0..6 out; 7: INIT (wave-0 in)

// wave_shr:1 = 0x138 (out[l]=in[l-1]; lane0<-old[0])   [verified R1..R5]
// wave_shl:1 = 0x130 (out[l]=in[l+1]; lane63<-old[63]) [verified R3/R5]
#define DPPF(old, src, ctrl)                                                     \
    __int_as_float(__builtin_amdgcn_update_dpp(                                  \
        __float_as_int(old), __float_as_int(src), (ctrl), 0xF, 0xF, false))

__global__ void dtw_pad_kernel(const float* __restrict__ x, float* __restrict__ xpad) {
    int i = blockIdx.x * blockDim.x + threadIdx.x;
    if (i < XPAD_TOTAL) {
        int j = i - PAD_L;
        xpad[i] = (j >= 0 && j < N_LEN) ? x[j] : BIGX;
    }
}

// One 64-diagonal chunk for one 64-column band. xc = this chunk's per-lane x
// window; xn gets filled with the NEXT chunk's window (consumed next call).
template <bool LAST>
__device__ __forceinline__ void dtw_chunk(int c, const float* __restrict__ xl,
                                          float (&xc)[64], float (&xn)[64],
                                          const float* __restrict__ ldsIn,
                                          float* __restrict__ ldsOut,
                                          float kk, float& A, float& E,
                                          int lane, float* __restrict__ out) {
    const int t0 = c * 64;
    const int rb = (c & 3) * 64;

    // Prefetch next chunk's x (64 independent scalar loads, consumed next chunk:
    // a full chunk of latency hiding; xpad is constant so no barrier ordering dep)
#pragma unroll
    for (int q = 0; q < 64; ++q) xn[q] = xl[t0 + 64 + q];

    // Boundary stream: lane r holds producer's E at diag t0+r-1 (r=0 wraps to
    // the previous chunk's last slot). Written before the last barrier.
    float B = ldsIn[(rb + lane + RING - 1) & (RING - 1)];

    float C = 0.0f; // collector: after 64 iters lane r holds iter r's lane-63 value

#pragma unroll
    for (int r = 0; r < 64; ++r) {
        // shifted E: lane l <- lane l-1's E; lane 0 <- B[0] (dpp old, bound_ctrl=0)
        const float esh = DPPF(B, E, 0x138);
        B = DPPF(B, B, 0x130);                 // advance boundary stream one slot
        const float t = kk - xc[r];
        const float na = __builtin_fmaf(t, t, fminf(A, esh));
        const float ne = fminf(na, A);
        // collect lane63: boundary E (waves 0-6) / output A[511] (wave 7)
        C = DPPF(LAST ? na : ne, C, 0x130);
        A = na; E = ne;
    }

    if (!LAST) {
        ldsOut[rb + lane] = C;                  // one full-wave ds_write per chunk
    } else {
        const int oi = t0 + lane - (K_LEN - 1);
        if (oi >= 0 && oi < N_LEN) out[oi] = C; // direct coalesced store
    }
}

__global__ __launch_bounds__(512, 1) void dtw_main(const float* __restrict__ xpad,
                                                   const float* __restrict__ kern,
                                                   float* __restrict__ out) {
    __shared__ float lds[NWAVE * RING];     // rings 0..6: wave w out; ring 7: INIT
    const float INFV = __builtin_inff();
    const int tid  = threadIdx.x;
    const int w    = __builtin_amdgcn_readfirstlane(tid) >> 6; // wave id 0..7 (SGPR)
    const int lane = tid & 63;

    // LDS init: all INF; INIT[255] = 0.0 is the DP seed ac[-1][-1]=0 (wave 0, t=0)
    for (int i = tid; i < NWAVE * RING; i += 512)
        lds[i] = (i == INIT_RING * RING + RING - 1) ? 0.0f : INFV;
    __syncthreads();

    const int j0 = w * 64 + lane;           // this lane's column
    const float kk = kern[j0];

    const float* xl = xpad + PAD_L - j0;    // per-lane x stream: x at diag t is xl[t]

    float* ldsOut      = lds + w * RING;                 // unused by wave 7
    const float* ldsIn = (w == 0) ? (lds + INIT_RING * RING) : (lds + (w - 1) * RING);

    float A = INFV, E = INFV;

    // per-lane x windows, ping-pong across chunks; preload chunk 0's window
    float xwA[64], xwB[64];
#pragma unroll
    for (int q = 0; q < 64; ++q) xwA[q] = xl[q];

    for (int S = 0; S < NCHUNK + NWAVE - 1; ++S) {
        const int c = S - w;                // chunk index for this wave (skewed pipeline)
        if (c >= 0 && c < NCHUNK) {
            if (c & 1) {
                if (w == NWAVE - 1) dtw_chunk<true >(c, xl, xwB, xwA, ldsIn, ldsOut, kk, A, E, lane, out);
                else                dtw_chunk<false>(c, xl, xwB, xwA, ldsIn, ldsOut, kk, A, E, lane, out);
            } else {
                if (w == NWAVE - 1) dtw_chunk<true >(c, xl, xwA, xwB, ldsIn, ldsOut, kk, A, E, lane, out);
                else                dtw_chunk<false>(c, xl, xwA, xwB, ldsIn, ldsOut, kk, A, E, lane, out);
            }
        }
        if (S == 0 && tid == 0) lds[INIT_RING * RING + RING - 1] = INFV; // retire seed
        __syncthreads();
    }
}

extern "C" void kernel_launch(void* const* d_in, const int* in_sizes, int n_in,
                              void* d_out, int out_size, void* d_ws, size_t ws_size,
                              hipStream_t stream) {
    const float* x = (const float*)d_in[0];   // input, 65536 fp32
    const float* k = (const float*)d_in[1];   // kernel, 512 fp32
    float* xpad = (float*)d_ws;               // needs 268288 B of scratch
    float* out  = (float*)d_out;              // 65536 fp32
    dtw_pad_kernel<<<(XPAD_TOTAL + 255) / 256, 256, 0, stream>>>(x, xpad);
    dtw_main<<<1, 512, 0, stream>>>(xpad, k, out);
}

// Round 7
// 2332.251 us; speedup vs baseline: 1.2804x; 1.2804x over previous
//
#include <hip/hip_runtime.h>

// DTW accumulated-cost, output = last column. N=65536 rows (input), K=512 cols (kernel).
// Anti-diagonal recurrence with E[j]=min(A_t[j],A_{t-1}[j]):
//   A_{t+1}[j] = min(A_t[j], E_t[j-1]) + (k[j]-x[i])^2 ,  i = t+1-j
// 4 waves (one per SIMD) split j into 128-wide bands (j = 128w + 2*lane + slot);
// skewed-chunk barrier pipeline passes band-boundary E values through LDS rings.
// R7: CHUNK 64 -> 128 diagonals per step. Step-time decomposition across R1-R6
// shows ~2900 cyc/step FIXED cost (barrier + waitcnt drain + resteer) vs ~2100
// cyc of work: halving step count (1035 -> 519) attacks the dominant term.
// RING stays 4 chunks deep (512): at 2-chunk depth the r=0 wrap-slot read races
// with the same-step producer writing chunk c+1.

#define K_LEN 512
#define N_LEN 65536
#define PAD_L 512
#define PAD_R 1024
#define XPAD_TOTAL (PAD_L + N_LEN + PAD_R) // 67072 floats = 268288 B of d_ws
#define BIGX 1e20f
#define CHUNK 128
#define NCHUNK 516                         // 516*128 = 66048 >= N+K-1 = 66047 diagonals
#define RING 512                           // 4 chunks of 128 per boundary ring

__global__ void dtw_pad_kernel(const float* __restrict__ x, float* __restrict__ xpad) {
    int i = blockIdx.x * blockDim.x + threadIdx.x;
    if (i < XPAD_TOTAL) {
        int j = i - PAD_L;
        xpad[i] = (j >= 0 && j < N_LEN) ? x[j] : BIGX;
    }
}

// One 128-diagonal chunk. xc = this chunk's x window (64 float2 = 128 x values),
// xn gets filled with the NEXT chunk's window (loads issued first, consumed next call).
template <bool LAST>
__device__ __forceinline__ void dtw_chunk(int c, const float* __restrict__ xl,
                                          float2 (&xc)[64], float2 (&xn)[64],
                                          const float* __restrict__ ldsIn,
                                          float* __restrict__ ldsOut,
                                          float k0, float k1,
                                          float& A0, float& A1, float& E0, float& E1,
                                          float& xp, int lane, float* __restrict__ out) {
    const int t0 = c * CHUNK;
    const int rb = (c & 3) * CHUNK;        // ring quarter for this chunk

    // Prefetch next chunk's x window (8B-aligned: float index PAD_L-2*lane+... is even).
    // Consumed only next chunk -> a full chunk of latency hiding.
    const float2* xnp = reinterpret_cast<const float2*>(xl + t0 + CHUNK);
#pragma unroll
    for (int q = 0; q < 64; ++q) xn[q] = xnp[q];

    // Boundary stream: iter r needs producer's E at diag t0+r-1.
    // B0: lane r (0..63) <- slot (rb+r-1) mod RING (r=0 wraps to prev chunk's last slot,
    //     which lives in ring quarter (c-1)&3 — same-step producer writes (c+1)&3: safe).
    // B1: lane r-64 <- slot rb+63+lane (r=64..127).
    const float B0 = ldsIn[(rb + lane + RING - 1) & (RING - 1)];
    const float B1 = ldsIn[rb + 63 + lane];

    float C0 = 0.0f, C1 = 0.0f; // collectors: lane r <- iter r / iter 64+r lane-63 value

#pragma unroll
    for (int r = 0; r < CHUNK; ++r) {
        const float xf = (r & 1) ? xc[r >> 1].y : xc[r >> 1].x; // slot-0 x this diagonal
        // boundary inject value (wave-uniform SGPR; r is a compile-time constant)
        const int sbi = __builtin_amdgcn_readlane(
            __float_as_int((r < 64) ? B0 : B1), r & 63);
        // slot-0 shifted E: lane l <- lane l-1's E1 (bound_ctrl=1 -> single mov_dpp)
        const float eshs = __int_as_float(__builtin_amdgcn_update_dpp(
            0, __float_as_int(E1), 0x138 /*wave_shr:1*/, 0xF, 0xF, true));
        // lane 0 <- boundary: v_cndmask with SGPR src + loop-invariant vcc mask
        const float esh0 = (lane != 0) ? eshs : __int_as_float(sbi);

        const float t0c = k0 - xf;
        const float t1c = k1 - xp;
        const float m0  = fminf(A0, esh0);
        const float m1  = fminf(A1, E0);          // slot-1 neighbor is same-lane slot 0
        const float na0 = __builtin_fmaf(t0c, t0c, m0);
        const float na1 = __builtin_fmaf(t1c, t1c, m1);
        const float ne0 = fminf(na0, A0);
        const float ne1 = fminf(na1, A1);

        // collect lane63's boundary E (waves 0-2) / output A[511] (wave 3):
        // rotating DPP collector (verified R3/R5): lane63 <- keepval, rest shift down
        const float keepv = LAST ? na1 : ne1;
        if (r < 64)
            C0 = __int_as_float(__builtin_amdgcn_update_dpp(
                __float_as_int(keepv), __float_as_int(C0), 0x130 /*wave_shl:1*/, 0xF, 0xF, false));
        else
            C1 = __int_as_float(__builtin_amdgcn_update_dpp(
                __float_as_int(keepv), __float_as_int(C1), 0x130 /*wave_shl:1*/, 0xF, 0xF, false));

        A0 = na0; A1 = na1; E0 = ne0; E1 = ne1; xp = xf;
    }

    if (!LAST) {
        ldsOut[rb + lane]      = C0;        // two full-wave ds_writes per chunk
        ldsOut[rb + 64 + lane] = C1;
    } else {
        const int oi0 = t0 + lane - (K_LEN - 1);
        const int oi1 = oi0 + 64;
        if (oi0 >= 0 && oi0 < N_LEN) out[oi0] = C0; // direct coalesced stores
        if (oi1 >= 0 && oi1 < N_LEN) out[oi1] = C1;
    }
}

__global__ __launch_bounds__(256, 1) void dtw_main(const float* __restrict__ xpad,
                                                   const float* __restrict__ kern,
                                                   float* __restrict__ out) {
    __shared__ float lds[5 * RING]; // rings 0..2: wave w out (ring 3 unused);
                                    // INIT ring at 4*RING read by wave 0
    const float INFV = __builtin_inff();
    const int tid  = threadIdx.x;
    const int w    = __builtin_amdgcn_readfirstlane(tid) >> 6; // wave id, uniform SGPR
    const int lane = tid & 63;

    // LDS init: all INF; INIT[RING-1] = 0.0 is the DP seed ac[-1][-1]=0 (wave 0, t=0)
    for (int i = tid; i < 5 * RING; i += 256)
        lds[i] = (i == 4 * RING + RING - 1) ? 0.0f : INFV;
    __syncthreads();

    const int j0 = w * 128 + 2 * lane;      // slot-0 column; slot-1 = j0+1
    const float k0 = kern[j0];
    const float k1 = kern[j0 + 1];

    const float* xl = xpad + PAD_L - j0;    // per-lane x stream: slot-0 x at diag t is xl[t]
    float xp = xl[-1];                      // slot-1 x entering t=0 (left pad)

    float* ldsOut      = lds + w * RING;
    const float* ldsIn = (w == 0) ? (lds + 4 * RING) : (lds + (w - 1) * RING);

    float A0 = INFV, A1 = INFV, E0 = INFV, E1 = INFV;

    // x register windows (128 floats each), ping-pong across chunks; preload chunk 0
    float2 xwA[64], xwB[64];
    {
        const float2* x0p = reinterpret_cast<const float2*>(xl);
#pragma unroll
        for (int q = 0; q < 64; ++q) xwA[q] = x0p[q];
    }

    for (int S = 0; S < NCHUNK + 3; ++S) {
        const int c = S - w;                // chunk index for this wave (skewed pipeline)
        if (c >= 0 && c < NCHUNK) {
            if (c & 1) {
                if (w == 3) dtw_chunk<true >(c, xl, xwB, xwA, ldsIn, ldsOut, k0, k1, A0, A1, E0, E1, xp, lane, out);
                else        dtw_chunk<false>(c, xl, xwB, xwA, ldsIn, ldsOut, k0, k1, A0, A1, E0, E1, xp, lane, out);
            } else {
                if (w == 3) dtw_chunk<true >(c, xl, xwA, xwB, ldsIn, ldsOut, k0, k1, A0, A1, E0, E1, xp, lane, out);
                else        dtw_chunk<false>(c, xl, xwA, xwB, ldsIn, ldsOut, k0, k1, A0, A1, E0, E1, xp, lane, out);
            }
        }
        if (S == 0 && tid == 0) lds[4 * RING + RING - 1] = INFV; // retire seed before ring wraps
        __syncthreads();
    }
}

extern "C" void kernel_launch(void* const* d_in, const int* in_sizes, int n_in,
                              void* d_out, int out_size, void* d_ws, size_t ws_size,
                              hipStream_t stream) {
    const float* x = (const float*)d_in[0];   // input, 65536 fp32
    const float* k = (const float*)d_in[1];   // kernel, 512 fp32
    float* xpad = (float*)d_ws;               // needs 268288 B of scratch
    float* out  = (float*)d_out;              // 65536 fp32
    dtw_pad_kernel<<<(XPAD_TOTAL + 255) / 256, 256, 0, stream>>>(x, xpad);
    dtw_main<<<1, 256, 0, stream>>>(xpad, k, out);
}